// Round 15
// baseline (909.040 us; speedup 1.0000x reference)
//
#include <hip/hip_runtime.h>
#include <hip/hip_fp16.h>
#include <math.h>

#define NUSERS 100000
#define NITEMS 50000
#define BATCH  64
#define ORDER  8
#define BSHIFT 9                                   // 512 rows per bucket
#define BROWS  (1 << BSHIFT)
#define NBUCKU ((NUSERS + BROWS - 1) >> BSHIFT)    // 196
#define NBUCKI ((NITEMS + BROWS - 1) >> BSHIFT)    // 98
#define CAPU 16384
#define CAPI 24576
#define S1_BLOCKS 512
#define NREP 4

// ---------------------------------------------------------------------------
// R14: rows padded to mult-16 edges (dummy index -> zero row), fixed-capacity
// buckets, inlined scales. R15: 16B/lane gathers -- a 128B fp16 row is 8
// lanes x Half8, so one wave VMEM instr covers 8 edges' chunks; slot=lane>>3
// takes 2 consecutive edges/iter (int2 idx + 2 gathers). VMEM instr count
// /2.7 (SpMMs are request-issue-bound: 2.7 TB/s fp16 vs 3.75 fp32, VALU 21%).
// Both SpMMs 4 rows/wave (padding removed the tails that broke 4-row in R12).
// ---------------------------------------------------------------------------

struct __align__(16) Half8 { __half2 h[4]; };
struct Coeffs { float v[ORDER + 1]; };

#define SLOT ((size_t)(NITEMS + 1) * BATCH)        // fp16 tau slot incl. zero row

// ---------------------------------------------------------------------------
// CSR build (unchanged from R14)
// ---------------------------------------------------------------------------
__global__ void init_bcur(int* __restrict__ bcurU, int* __restrict__ bcurI) {
    int t = blockIdx.x * blockDim.x + threadIdx.x;
    if (t < NBUCKU) bcurU[t] = t * CAPU;
    if (t < NBUCKI) bcurI[t] = t * CAPI;
}

__global__ void zero_pads(__half* __restrict__ tauHall, __half* __restrict__ ybuf) {
    int t = threadIdx.x;
    for (int k = 0; k <= ORDER; ++k)
        if (t < BATCH) tauHall[(size_t)k * SLOT + (size_t)NITEMS * BATCH + t] = __float2half(0.f);
    if (t < BATCH) ybuf[(size_t)NUSERS * BATCH + t] = __float2half(0.f);
}

__global__ void scatter1(const int* __restrict__ row, const int* __restrict__ col,
                         int* __restrict__ bcurU, int* __restrict__ bcurI,
                         int* __restrict__ stU, int* __restrict__ stI, int nnz) {
    __shared__ int cU[NREP][NBUCKU];
    __shared__ int cI[NREP][NBUCKI];
    const int chunk = (nnz + S1_BLOCKS - 1) / S1_BLOCKS;
    const int b0 = blockIdx.x * chunk;
    const int e0 = min(b0 + chunk, nnz);
    const int sw = threadIdx.x >> 6;
    for (int t = threadIdx.x; t < NREP * NBUCKU; t += blockDim.x) (&cU[0][0])[t] = 0;
    for (int t = threadIdx.x; t < NREP * NBUCKI; t += blockDim.x) (&cI[0][0])[t] = 0;
    __syncthreads();
    for (int i = b0 + threadIdx.x; i < e0; i += blockDim.x) {
        atomicAdd(&cU[sw][row[i] >> BSHIFT], 1);
        atomicAdd(&cI[sw][col[i] >> BSHIFT], 1);
    }
    __syncthreads();
    for (int t = threadIdx.x; t < NBUCKU; t += blockDim.x) {
        int c0 = cU[0][t], c1 = cU[1][t], c2 = cU[2][t], c3 = cU[3][t];
        int tot = c0 + c1 + c2 + c3;
        int base = (tot > 0) ? atomicAdd(&bcurU[t], tot) : 0;
        cU[0][t] = base;
        cU[1][t] = base + c0;
        cU[2][t] = base + c0 + c1;
        cU[3][t] = base + c0 + c1 + c2;
    }
    for (int t = threadIdx.x; t < NBUCKI; t += blockDim.x) {
        int c0 = cI[0][t], c1 = cI[1][t], c2 = cI[2][t], c3 = cI[3][t];
        int tot = c0 + c1 + c2 + c3;
        int base = (tot > 0) ? atomicAdd(&bcurI[t], tot) : 0;
        cI[0][t] = base;
        cI[1][t] = base + c0;
        cI[2][t] = base + c0 + c1;
        cI[3][t] = base + c0 + c1 + c2;
    }
    __syncthreads();
    for (int i = b0 + threadIdx.x; i < e0; i += blockDim.x) {
        int r = row[i], c = col[i];
        int pu = atomicAdd(&cU[sw][r >> BSHIFT], 1);
        stU[pu] = ((r & (BROWS - 1)) << 17) | c;
        int pi = atomicAdd(&cI[sw][c >> BSHIFT], 1);
        stI[pi] = ((c & (BROWS - 1)) << 17) | r;
    }
}

__global__ void scatter2(const int* __restrict__ bcur, const int* __restrict__ st,
                         int* __restrict__ ptr, int* __restrict__ degOut,
                         int* __restrict__ outIdx, int nrows, int cap, int dummyIdx) {
    __shared__ int deg[BROWS];
    __shared__ int ps[256];
    __shared__ int cur[BROWS];
    __shared__ int rs[BROWS];
    const int rbase = blockIdx.x << BSHIFT;
    const int nr = min(BROWS, nrows - rbase);
    const int lo = blockIdx.x * cap;
    const int hi = bcur[blockIdx.x];
    const int t = threadIdx.x;
    deg[2 * t] = 0;
    deg[2 * t + 1] = 0;
    __syncthreads();
    for (int j = lo + t; j < hi; j += 256)
        atomicAdd(&deg[st[j] >> 17], 1);
    __syncthreads();
    int a = deg[2 * t];
    int b = deg[2 * t + 1];
    int pa = (a + 15) & ~15;
    int pb = (b + 15) & ~15;
    ps[t] = pa + pb;
    __syncthreads();
    for (int off = 1; off < 256; off <<= 1) {
        int u = (t >= off) ? ps[t - off] : 0;
        __syncthreads();
        ps[t] += u;
        __syncthreads();
    }
    int excl = (t > 0) ? ps[t - 1] : 0;
    int p0 = lo + excl;
    int p1 = p0 + pa;
    rs[2 * t] = p0;
    rs[2 * t + 1] = p1;
    cur[2 * t] = p0;
    cur[2 * t + 1] = p1;
    if (2 * t < nr)     { ptr[rbase + 2 * t] = p0;     degOut[rbase + 2 * t] = a; }
    if (2 * t + 1 < nr) { ptr[rbase + 2 * t + 1] = p1; degOut[rbase + 2 * t + 1] = b; }
    __syncthreads();
    for (int j = lo + t; j < hi; j += 256) {
        int v = st[j];
        int p = atomicAdd(&cur[v >> 17], 1);
        outIdx[p] = v & 0x1FFFF;
    }
    __syncthreads();
    for (int i = t; i < nr; i += 256) {
        int endReal = cur[i];
        int endPad  = rs[i] + ((deg[i] + 15) & ~15);
        for (int j = endReal; j < endPad; ++j) outIdx[j] = dummyIdx;
    }
}

// ---------------------------------------------------------------------------
// transposes (unchanged)
// ---------------------------------------------------------------------------
__global__ void transpose_scale_k(const float* __restrict__ in,
                                  const int* __restrict__ ideg,
                                  float* __restrict__ out,
                                  __half* __restrict__ outH) {
    __shared__ float tile[32][33];
    const int cb = blockIdx.x * 32;
    const int rb = blockIdx.y * 32;
    for (int i = threadIdx.y; i < 32; i += 8) {
        int r = rb + i, c = cb + threadIdx.x;
        if (r < BATCH && c < NITEMS) tile[i][threadIdx.x] = in[(size_t)r * NITEMS + c];
    }
    __syncthreads();
    for (int i = threadIdx.y; i < 32; i += 8) {
        int c = cb + i, r = rb + threadIdx.x;
        if (c < NITEMS && r < BATCH) {
            int d = ideg[c];
            float dis = (d > 0) ? rsqrtf((float)d) : 0.0f;
            float v = dis * tile[threadIdx.x][i];
            out[(size_t)c * BATCH + r] = v;
            outH[(size_t)c * BATCH + r] = __float2half(v);
        }
    }
}

__global__ void transpose_out_k(const __half* __restrict__ tauHall,
                                const float* __restrict__ signal,
                                const int* __restrict__ ideg, float csum, Coeffs cf,
                                float* __restrict__ out) {
    __shared__ float tile[32][33];
    const int cb = blockIdx.x * 32;
    const int rb = blockIdx.y * 32;
    for (int i = threadIdx.y; i < 32; i += 8) {
        int r = rb + i, c = cb + threadIdx.x;
        if (r < NITEMS && c < BATCH) {
            size_t base = (size_t)r * BATCH + c;
            float s = 0.f;
            #pragma unroll
            for (int k = 0; k <= ORDER; ++k)
                s += cf.v[k] * __half2float(tauHall[(size_t)k * SLOT + base]);
            tile[i][threadIdx.x] = s;
        }
    }
    __syncthreads();
    for (int i = threadIdx.y; i < 32; i += 8) {
        int c = cb + i, r = rb + threadIdx.x;
        if (c < BATCH && r < NITEMS) {
            int d = ideg[r];
            float v = (d > 0) ? sqrtf((float)d) * tile[threadIdx.x][i]
                              : csum * signal[(size_t)c * NITEMS + r];
            out[(size_t)c * NITEMS + r] = v;
        }
    }
}

// ---------------------------------------------------------------------------
// 4-row gather core, 16B/lane: slot=lane>>3 (8 slots), bh=lane&7 (16B chunk).
// Per macro-iter each slot handles 2 consecutive edges: int2 idx + 2 Half8
// gathers. Rows padded to mult-16 -> exactly n=(deg+15)>>4 iters, no tails.
// Cross-slot reduce: shfl_xor 8,16,32.
// ---------------------------------------------------------------------------
__device__ __forceinline__ void gather4x2(const int* __restrict__ idx,
                                          const Half8* __restrict__ x,
                                          const int* b, const int* n,
                                          int slot, int bh, float (*a)[8]) {
    int j[4];
    int nmax = 0;
    #pragma unroll
    for (int q = 0; q < 4; ++q) {
        j[q] = b[q] + slot * 2;
        nmax = max(nmax, n[q]);
    }
    for (int it = 0; it < nmax; ++it) {
        #pragma unroll
        for (int q = 0; q < 4; ++q) {
            if (it < n[q]) {
                int2 ii = *(const int2*)&idx[j[q]];
                Half8 v0 = x[(size_t)ii.x * 8 + bh];
                Half8 v1 = x[(size_t)ii.y * 8 + bh];
                #pragma unroll
                for (int k = 0; k < 4; ++k) {
                    __half2 s = __hadd2(v0.h[k], v1.h[k]);
                    float2 f = __half22float2(s);
                    a[q][2 * k]     += f.x;
                    a[q][2 * k + 1] += f.y;
                }
                j[q] += 16;
            }
        }
    }
    #pragma unroll
    for (int q = 0; q < 4; ++q) {
        #pragma unroll
        for (int k = 0; k < 8; ++k) {
            a[q][k] += __shfl_xor(a[q][k], 8);
            a[q][k] += __shfl_xor(a[q][k], 16);
            a[q][k] += __shfl_xor(a[q][k], 32);
        }
    }
}

// user side (4 rows/wave): y[u] = (1/deg_u) * sum tauH[col]
__global__ void spmm_user(const int* __restrict__ ptr, const int* __restrict__ deg,
                          const int* __restrict__ idx,
                          const Half8* __restrict__ tauH, Half8* __restrict__ y) {
    const int lane = threadIdx.x & 63;
    const int w = (blockIdx.x * blockDim.x + threadIdx.x) >> 6;
    const int H = NUSERS / 4;
    if (w >= H) return;
    int r[4] = {w, w + H, w + 2 * H, w + 3 * H};
    const int slot = lane >> 3;
    const int bh   = lane & 7;
    int b[4], d[4], n[4];
    #pragma unroll
    for (int q = 0; q < 4; ++q) {
        b[q] = ptr[r[q]];
        d[q] = deg[r[q]];
        n[q] = (d[q] + 15) >> 4;
    }
    float a[4][8] = {};
    gather4x2(idx, tauH, b, n, slot, bh, a);
    if (slot == 0) {
        #pragma unroll
        for (int q = 0; q < 4; ++q) {
            float s = (d[q] > 0) ? 1.0f / (float)d[q] : 0.0f;
            Half8 o;
            #pragma unroll
            for (int k = 0; k < 4; ++k)
                o.h[k] = __floats2half2_rn(s * a[q][2 * k], s * a[q][2 * k + 1]);
            y[(size_t)r[q] * 8 + bh] = o;
        }
    }
}

// item, first step: tau1 = tau0 - (2/deg)*z ; write fp32 + fp16
__global__ void spmm_item_first(const int* __restrict__ ptr, const int* __restrict__ deg,
                                const int* __restrict__ idx, const Half8* __restrict__ y,
                                const float* __restrict__ tau0, float* __restrict__ tau1,
                                Half8* __restrict__ tauH1) {
    const int lane = threadIdx.x & 63;
    const int w = (blockIdx.x * blockDim.x + threadIdx.x) >> 6;
    const int H = NITEMS / 4;
    if (w >= H) return;
    int r[4] = {w, w + H, w + 2 * H, w + 3 * H};
    const int slot = lane >> 3;
    const int bh   = lane & 7;
    int b[4], d[4], n[4];
    #pragma unroll
    for (int q = 0; q < 4; ++q) {
        b[q] = ptr[r[q]];
        d[q] = deg[r[q]];
        n[q] = (d[q] + 15) >> 4;
    }
    float a[4][8] = {};
    gather4x2(idx, y, b, n, slot, bh, a);
    if (slot == 0) {
        #pragma unroll
        for (int q = 0; q < 4; ++q) {
            float inv = (d[q] > 0) ? 1.0f / (float)d[q] : 0.0f;
            float s2 = 2.0f * inv;
            size_t base = (size_t)r[q] * BATCH + bh * 8;
            float4 t0a = *(const float4*)&tau0[base];
            float4 t0b = *(const float4*)&tau0[base + 4];
            float4 ta, tb;
            ta.x = t0a.x - s2 * a[q][0]; ta.y = t0a.y - s2 * a[q][1];
            ta.z = t0a.z - s2 * a[q][2]; ta.w = t0a.w - s2 * a[q][3];
            tb.x = t0b.x - s2 * a[q][4]; tb.y = t0b.y - s2 * a[q][5];
            tb.z = t0b.z - s2 * a[q][6]; tb.w = t0b.w - s2 * a[q][7];
            *(float4*)&tau1[base] = ta;
            *(float4*)&tau1[base + 4] = tb;
            Half8 o;
            o.h[0] = __floats2half2_rn(ta.x, ta.y);
            o.h[1] = __floats2half2_rn(ta.z, ta.w);
            o.h[2] = __floats2half2_rn(tb.x, tb.y);
            o.h[3] = __floats2half2_rn(tb.z, tb.w);
            tauH1[(size_t)r[q] * 8 + bh] = o;
        }
    }
}

// item, general step: t2 = 2*t1 - (4/deg)*z - t0 ; write fp32 + fp16
__global__ void spmm_item_k(const int* __restrict__ ptr, const int* __restrict__ deg,
                            const int* __restrict__ idx, const Half8* __restrict__ y,
                            const float* __restrict__ tau1, float* __restrict__ tau0,
                            Half8* __restrict__ tauHk) {
    const int lane = threadIdx.x & 63;
    const int w = (blockIdx.x * blockDim.x + threadIdx.x) >> 6;
    const int H = NITEMS / 4;
    if (w >= H) return;
    int r[4] = {w, w + H, w + 2 * H, w + 3 * H};
    const int slot = lane >> 3;
    const int bh   = lane & 7;
    int b[4], d[4], n[4];
    #pragma unroll
    for (int q = 0; q < 4; ++q) {
        b[q] = ptr[r[q]];
        d[q] = deg[r[q]];
        n[q] = (d[q] + 15) >> 4;
    }
    float a[4][8] = {};
    gather4x2(idx, y, b, n, slot, bh, a);
    if (slot == 0) {
        #pragma unroll
        for (int q = 0; q < 4; ++q) {
            float inv = (d[q] > 0) ? 1.0f / (float)d[q] : 0.0f;
            float s4 = 4.0f * inv;
            size_t base = (size_t)r[q] * BATCH + bh * 8;
            float4 t1a = *(const float4*)&tau1[base];
            float4 t1b = *(const float4*)&tau1[base + 4];
            float4 t0a = *(const float4*)&tau0[base];
            float4 t0b = *(const float4*)&tau0[base + 4];
            float4 ta, tb;
            ta.x = 2.0f * t1a.x - s4 * a[q][0] - t0a.x;
            ta.y = 2.0f * t1a.y - s4 * a[q][1] - t0a.y;
            ta.z = 2.0f * t1a.z - s4 * a[q][2] - t0a.z;
            ta.w = 2.0f * t1a.w - s4 * a[q][3] - t0a.w;
            tb.x = 2.0f * t1b.x - s4 * a[q][4] - t0b.x;
            tb.y = 2.0f * t1b.y - s4 * a[q][5] - t0b.y;
            tb.z = 2.0f * t1b.z - s4 * a[q][6] - t0b.z;
            tb.w = 2.0f * t1b.w - s4 * a[q][7] - t0b.w;
            *(float4*)&tau0[base] = ta;
            *(float4*)&tau0[base + 4] = tb;
            Half8 o;
            o.h[0] = __floats2half2_rn(ta.x, ta.y);
            o.h[1] = __floats2half2_rn(ta.z, ta.w);
            o.h[2] = __floats2half2_rn(tb.x, tb.y);
            o.h[3] = __floats2half2_rn(tb.z, tb.w);
            tauHk[(size_t)r[q] * 8 + bh] = o;
        }
    }
}

// ---------------------------------------------------------------------------
// Host-side exact replica of reference cheby_coeffs
// ---------------------------------------------------------------------------
static void cheby_coeffs_host(float* c) {
    const int order = ORDER, flatness = 2;
    const double PI = 3.14159265358979323846;
    double tgt[ORDER + 1], nodes[ORDER + 1];
    for (int x = 0; x <= order; ++x) {
        double xv = cos((double)(order - x) / order * PI);
        xv = nearbyint(xv * 1000.0) / 1000.0;
        double t = (xv < 0.0) ? pow(-xv, (double)flatness) * 0.5 + 0.5
                              : pow(xv, (double)flatness) * (-0.5) + 0.5;
        tgt[x] = nearbyint(t * 1000.0) / 1000.0;
    }
    for (int k = 1; k <= order + 1; ++k)
        nodes[k - 1] = cos((order + 1 + 0.5 - k) / (double)(order + 1) * PI);

    double prev[ORDER + 1], cur[ORDER + 1], nxt[ORDER + 1];
    double sums[ORDER + 1];
    double s0 = 0, s1 = 0;
    for (int i = 0; i <= order; ++i) {
        prev[i] = tgt[i];
        cur[i]  = nodes[i] * tgt[i];
        s0 += prev[i];
        s1 += cur[i];
    }
    sums[0] = s0; sums[1] = s1;
    for (int j = 2; j <= order; ++j) {
        double s = 0;
        for (int i = 0; i <= order; ++i) {
            nxt[i] = nodes[i] * cur[i] * 2.0 - prev[i];
            s += nxt[i];
        }
        sums[j] = s;
        for (int i = 0; i <= order; ++i) { prev[i] = cur[i]; cur[i] = nxt[i]; }
    }
    for (int j = 0; j <= order; ++j)
        c[j] = (float)(sums[j] * (2.0 / (order + 1)));
    c[0] *= 0.5f;
}

extern "C" void kernel_launch(void* const* d_in, const int* in_sizes, int n_in,
                              void* d_out, int out_size, void* d_ws, size_t ws_size,
                              hipStream_t stream) {
    const float* signal = (const float*)d_in[0];   // [BATCH, NITEMS]
    const int*   row    = (const int*)d_in[2];     // [NNZ] -> users
    const int*   col    = (const int*)d_in[3];     // [NNZ] -> items
    const int nnz = in_sizes[1];

    char* wsb = (char*)d_ws;
    size_t off = 0;
    auto carve = [&](size_t nbytes) {
        void* p = wsb + off;
        off += (nbytes + 255) & ~(size_t)255;
        return p;
    };
    const size_t NB = (size_t)NITEMS * BATCH;
    const size_t NEU = (size_t)NBUCKU * CAPU;
    const size_t NEI = (size_t)NBUCKI * CAPI;
    float*  tauA   = (float*)carve(NB * 4);
    float*  tauB   = (float*)carve(NB * 4);
    __half* tauHall = (__half*)carve((ORDER + 1) * SLOT * 2);
    Half8*  ybuf   = (Half8*)carve(((size_t)NUSERS + 1) * BATCH * 2);
    int*    uptr   = (int*)carve(NUSERS * 4);
    int*    iptr   = (int*)carve(NITEMS * 4);
    int*    udeg   = (int*)carve(NUSERS * 4);
    int*    ideg   = (int*)carve(NITEMS * 4);
    int*    bcurU  = (int*)carve(NBUCKU * 4);
    int*    bcurI  = (int*)carve(NBUCKI * 4);
    int*    ucol   = (int*)carve(NEU * 4);
    int*    irow   = (int*)carve(NEI * 4);
    int*    stU    = (int*)tauHall;                // staging aliases tauHall
    int*    stI    = (int*)tauHall + NEU;
    (void)ws_size;

    float c[ORDER + 1];
    cheby_coeffs_host(c);
    Coeffs cf;
    float csum = 0.f;
    for (int k = 0; k <= ORDER; ++k) { cf.v[k] = c[k]; csum += c[k]; }

    // ---- CSR build ----
    init_bcur<<<(NBUCKU + 255) / 256, 256, 0, stream>>>(bcurU, bcurI);
    scatter1<<<S1_BLOCKS, 256, 0, stream>>>(row, col, bcurU, bcurI, stU, stI, nnz);
    scatter2<<<NBUCKU, 256, 0, stream>>>(bcurU, stU, uptr, udeg, ucol, NUSERS, CAPU, NITEMS);
    scatter2<<<NBUCKI, 256, 0, stream>>>(bcurI, stI, iptr, ideg, irow, NITEMS, CAPI, NUSERS);
    zero_pads<<<1, 256, 0, stream>>>(tauHall, (__half*)ybuf);

    // ---- tau0 (fp32 + fp16 slot 0) ----
    dim3 tb(32, 8);
    transpose_scale_k<<<dim3((NITEMS + 31) / 32, (BATCH + 31) / 32), tb, 0, stream>>>(
        signal, ideg, tauA, tauHall);

    const int ug = ((NUSERS / 4) * 64 + 255) / 256;   // 4 rows/wave
    const int ig = ((NITEMS / 4) * 64 + 255) / 256;

    // ---- k = 1 ----
    spmm_user<<<ug, 256, 0, stream>>>(uptr, udeg, ucol, (const Half8*)tauHall, ybuf);
    spmm_item_first<<<ig, 256, 0, stream>>>(iptr, ideg, irow, ybuf, tauA, tauB,
                                            (Half8*)(tauHall + SLOT));

    float* t0 = tauA;
    float* t1 = tauB;
    for (int k = 2; k <= ORDER; ++k) {
        spmm_user<<<ug, 256, 0, stream>>>(uptr, udeg, ucol,
                                          (const Half8*)(tauHall + (size_t)(k - 1) * SLOT), ybuf);
        spmm_item_k<<<ig, 256, 0, stream>>>(iptr, ideg, irow, ybuf, t1, t0,
                                            (Half8*)(tauHall + (size_t)k * SLOT));
        float* tmp = t0; t0 = t1; t1 = tmp;
    }

    // ---- d_out = sqrt(di) * sum_k c_k tauH_k, transposed ----
    transpose_out_k<<<dim3((BATCH + 31) / 32, (NITEMS + 31) / 32), tb, 0, stream>>>(
        tauHall, signal, ideg, csum, cf, (float*)d_out);
}

// Round 16
// 805.666 us; speedup vs baseline: 1.1283x; 1.1283x over previous
//
#include <hip/hip_runtime.h>
#include <hip/hip_fp16.h>
#include <math.h>

#define NUSERS 100000
#define NITEMS 50000
#define BATCH  64
#define ORDER  8
#define BSHIFT 9                                   // 512 rows per bucket
#define BROWS  (1 << BSHIFT)
#define NBUCKU ((NUSERS + BROWS - 1) >> BSHIFT)    // 196
#define NBUCKI ((NITEMS + BROWS - 1) >> BSHIFT)    // 98
#define CAPU 16384
#define CAPI 24576
#define S1_BLOCKS 512
#define NREP 4
#define NBIN 16                                    // bins of n=(deg+15)>>4
#define BIN_BLOCKS 64

// ---------------------------------------------------------------------------
// R14 structure (best: 771us): padded rows (dummy->zero row), fixed-capacity
// buckets, inlined scales, fp16 gathers 8B/lane, 2-row user / 4-row item.
// R15 (16B/lane) regressed: lines/instr is invariant, VGPR+occupancy suffered
// -- reverted. R16: bin-sorted row scheduling -- counting-sort rows by padded
// iter count n into perm[]; wave takes perm[kw..kw+k-1] so co-scheduled rows
// have identical n (E[max4]~2.97 vs E[n]~2.47 was ~17% wasted iters on item,
// ~13% on user). Bit-identical numerics; pure scheduling.
// ---------------------------------------------------------------------------

struct __align__(8) Half4 { __half2 a, b; };
struct Coeffs { float v[ORDER + 1]; };

#define SLOT ((size_t)(NITEMS + 1) * BATCH)        // fp16 tau slot incl. zero row

__device__ __forceinline__ void acc_pk(float4& acc, Half4 v0, Half4 v1,
                                       Half4 v2, Half4 v3) {
    __half2 sa = __hadd2(__hadd2(v0.a, v1.a), __hadd2(v2.a, v3.a));
    __half2 sb = __hadd2(__hadd2(v0.b, v1.b), __hadd2(v2.b, v3.b));
    float2 fa = __half22float2(sa);
    float2 fb = __half22float2(sb);
    acc.x += fa.x; acc.y += fa.y; acc.z += fb.x; acc.w += fb.y;
}

__device__ __forceinline__ Half4 to_h4(float x, float y, float z, float w) {
    Half4 h;
    h.a = __floats2half2_rn(x, y);
    h.b = __floats2half2_rn(z, w);
    return h;
}

// ---------------------------------------------------------------------------
// CSR build (R14)
// ---------------------------------------------------------------------------
__global__ void init_bcur(int* __restrict__ bcurU, int* __restrict__ bcurI,
                          int* __restrict__ bins) {
    int t = blockIdx.x * blockDim.x + threadIdx.x;
    if (t < NBUCKU) bcurU[t] = t * CAPU;
    if (t < NBUCKI) bcurI[t] = t * CAPI;
    if (t < 4 * NBIN) bins[t] = 0;                 // gcntU,gcurU,gcntI,gcurI
}

__global__ void zero_pads(__half* __restrict__ tauHall, __half* __restrict__ ybuf) {
    int t = threadIdx.x;
    for (int k = 0; k <= ORDER; ++k)
        if (t < BATCH) tauHall[(size_t)k * SLOT + (size_t)NITEMS * BATCH + t] = __float2half(0.f);
    if (t < BATCH) ybuf[(size_t)NUSERS * BATCH + t] = __float2half(0.f);
}

__global__ void scatter1(const int* __restrict__ row, const int* __restrict__ col,
                         int* __restrict__ bcurU, int* __restrict__ bcurI,
                         int* __restrict__ stU, int* __restrict__ stI, int nnz) {
    __shared__ int cU[NREP][NBUCKU];
    __shared__ int cI[NREP][NBUCKI];
    const int chunk = (nnz + S1_BLOCKS - 1) / S1_BLOCKS;
    const int b0 = blockIdx.x * chunk;
    const int e0 = min(b0 + chunk, nnz);
    const int sw = threadIdx.x >> 6;
    for (int t = threadIdx.x; t < NREP * NBUCKU; t += blockDim.x) (&cU[0][0])[t] = 0;
    for (int t = threadIdx.x; t < NREP * NBUCKI; t += blockDim.x) (&cI[0][0])[t] = 0;
    __syncthreads();
    for (int i = b0 + threadIdx.x; i < e0; i += blockDim.x) {
        atomicAdd(&cU[sw][row[i] >> BSHIFT], 1);
        atomicAdd(&cI[sw][col[i] >> BSHIFT], 1);
    }
    __syncthreads();
    for (int t = threadIdx.x; t < NBUCKU; t += blockDim.x) {
        int c0 = cU[0][t], c1 = cU[1][t], c2 = cU[2][t], c3 = cU[3][t];
        int tot = c0 + c1 + c2 + c3;
        int base = (tot > 0) ? atomicAdd(&bcurU[t], tot) : 0;
        cU[0][t] = base;
        cU[1][t] = base + c0;
        cU[2][t] = base + c0 + c1;
        cU[3][t] = base + c0 + c1 + c2;
    }
    for (int t = threadIdx.x; t < NBUCKI; t += blockDim.x) {
        int c0 = cI[0][t], c1 = cI[1][t], c2 = cI[2][t], c3 = cI[3][t];
        int tot = c0 + c1 + c2 + c3;
        int base = (tot > 0) ? atomicAdd(&bcurI[t], tot) : 0;
        cI[0][t] = base;
        cI[1][t] = base + c0;
        cI[2][t] = base + c0 + c1;
        cI[3][t] = base + c0 + c1 + c2;
    }
    __syncthreads();
    for (int i = b0 + threadIdx.x; i < e0; i += blockDim.x) {
        int r = row[i], c = col[i];
        int pu = atomicAdd(&cU[sw][r >> BSHIFT], 1);
        stU[pu] = ((r & (BROWS - 1)) << 17) | c;
        int pi = atomicAdd(&cI[sw][c >> BSHIFT], 1);
        stI[pi] = ((c & (BROWS - 1)) << 17) | r;
    }
}

__global__ void scatter2(const int* __restrict__ bcur, const int* __restrict__ st,
                         int* __restrict__ ptr, int* __restrict__ degOut,
                         int* __restrict__ outIdx, int nrows, int cap, int dummyIdx) {
    __shared__ int deg[BROWS];
    __shared__ int ps[256];
    __shared__ int cur[BROWS];
    __shared__ int rs[BROWS];
    const int rbase = blockIdx.x << BSHIFT;
    const int nr = min(BROWS, nrows - rbase);
    const int lo = blockIdx.x * cap;
    const int hi = bcur[blockIdx.x];
    const int t = threadIdx.x;
    deg[2 * t] = 0;
    deg[2 * t + 1] = 0;
    __syncthreads();
    for (int j = lo + t; j < hi; j += 256)
        atomicAdd(&deg[st[j] >> 17], 1);
    __syncthreads();
    int a = deg[2 * t];
    int b = deg[2 * t + 1];
    int pa = (a + 15) & ~15;
    int pb = (b + 15) & ~15;
    ps[t] = pa + pb;
    __syncthreads();
    for (int off = 1; off < 256; off <<= 1) {
        int u = (t >= off) ? ps[t - off] : 0;
        __syncthreads();
        ps[t] += u;
        __syncthreads();
    }
    int excl = (t > 0) ? ps[t - 1] : 0;
    int p0 = lo + excl;
    int p1 = p0 + pa;
    rs[2 * t] = p0;
    rs[2 * t + 1] = p1;
    cur[2 * t] = p0;
    cur[2 * t + 1] = p1;
    if (2 * t < nr)     { ptr[rbase + 2 * t] = p0;     degOut[rbase + 2 * t] = a; }
    if (2 * t + 1 < nr) { ptr[rbase + 2 * t + 1] = p1; degOut[rbase + 2 * t + 1] = b; }
    __syncthreads();
    for (int j = lo + t; j < hi; j += 256) {
        int v = st[j];
        int p = atomicAdd(&cur[v >> 17], 1);
        outIdx[p] = v & 0x1FFFF;
    }
    __syncthreads();
    for (int i = t; i < nr; i += 256) {
        int endReal = cur[i];
        int endPad  = rs[i] + ((deg[i] + 15) & ~15);
        for (int j = endReal; j < endPad; ++j) outIdx[j] = dummyIdx;
    }
}

// ---------------------------------------------------------------------------
// Bin-sort rows by padded iter count n=(deg+15)>>4 (counting sort, NBIN bins,
// block-aggregated reservations -- the R8-proven pattern).
// ---------------------------------------------------------------------------
__global__ void bin_count(const int* __restrict__ deg, int n, int* __restrict__ gcnt) {
    __shared__ int ls[NREP][NBIN];
    const int sw = threadIdx.x >> 6;
    for (int t = threadIdx.x; t < NREP * NBIN; t += blockDim.x) (&ls[0][0])[t] = 0;
    __syncthreads();
    const int chunk = (n + BIN_BLOCKS - 1) / BIN_BLOCKS;
    const int b0 = blockIdx.x * chunk;
    const int e0 = min(b0 + chunk, n);
    for (int i = b0 + threadIdx.x; i < e0; i += blockDim.x)
        atomicAdd(&ls[sw][min((deg[i] + 15) >> 4, NBIN - 1)], 1);
    __syncthreads();
    for (int t = threadIdx.x; t < NBIN; t += blockDim.x) {
        int s = ls[0][t] + ls[1][t] + ls[2][t] + ls[3][t];
        if (s > 0) atomicAdd(&gcnt[t], s);
    }
}

__global__ void bin_scan(int* __restrict__ bins) {   // gcntU,gcurU,gcntI,gcurI
    if (threadIdx.x == 0) {
        int s = 0;
        for (int i = 0; i < NBIN; ++i) { int v = bins[i]; bins[NBIN + i] = s; s += v; }
        s = 0;
        for (int i = 0; i < NBIN; ++i) { int v = bins[2 * NBIN + i]; bins[3 * NBIN + i] = s; s += v; }
    }
}

__global__ void bin_scatter(const int* __restrict__ deg, int n,
                            int* __restrict__ gcur, int* __restrict__ perm) {
    __shared__ int ls[NREP][NBIN];
    const int sw = threadIdx.x >> 6;
    for (int t = threadIdx.x; t < NREP * NBIN; t += blockDim.x) (&ls[0][0])[t] = 0;
    __syncthreads();
    const int chunk = (n + BIN_BLOCKS - 1) / BIN_BLOCKS;
    const int b0 = blockIdx.x * chunk;
    const int e0 = min(b0 + chunk, n);
    for (int i = b0 + threadIdx.x; i < e0; i += blockDim.x)
        atomicAdd(&ls[sw][min((deg[i] + 15) >> 4, NBIN - 1)], 1);
    __syncthreads();
    for (int t = threadIdx.x; t < NBIN; t += blockDim.x) {
        int c0 = ls[0][t], c1 = ls[1][t], c2 = ls[2][t], c3 = ls[3][t];
        int tot = c0 + c1 + c2 + c3;
        int base = (tot > 0) ? atomicAdd(&gcur[t], tot) : 0;
        ls[0][t] = base;
        ls[1][t] = base + c0;
        ls[2][t] = base + c0 + c1;
        ls[3][t] = base + c0 + c1 + c2;
    }
    __syncthreads();
    for (int i = b0 + threadIdx.x; i < e0; i += blockDim.x) {
        int bn = min((deg[i] + 15) >> 4, NBIN - 1);
        int p = atomicAdd(&ls[sw][bn], 1);
        perm[p] = i;
    }
}

// ---------------------------------------------------------------------------
// transposes (R14)
// ---------------------------------------------------------------------------
__global__ void transpose_scale_k(const float* __restrict__ in,
                                  const int* __restrict__ ideg,
                                  float* __restrict__ out,
                                  __half* __restrict__ outH) {
    __shared__ float tile[32][33];
    const int cb = blockIdx.x * 32;
    const int rb = blockIdx.y * 32;
    for (int i = threadIdx.y; i < 32; i += 8) {
        int r = rb + i, c = cb + threadIdx.x;
        if (r < BATCH && c < NITEMS) tile[i][threadIdx.x] = in[(size_t)r * NITEMS + c];
    }
    __syncthreads();
    for (int i = threadIdx.y; i < 32; i += 8) {
        int c = cb + i, r = rb + threadIdx.x;
        if (c < NITEMS && r < BATCH) {
            int d = ideg[c];
            float dis = (d > 0) ? rsqrtf((float)d) : 0.0f;
            float v = dis * tile[threadIdx.x][i];
            out[(size_t)c * BATCH + r] = v;
            outH[(size_t)c * BATCH + r] = __float2half(v);
        }
    }
}

__global__ void transpose_out_k(const __half* __restrict__ tauHall,
                                const float* __restrict__ signal,
                                const int* __restrict__ ideg, float csum, Coeffs cf,
                                float* __restrict__ out) {
    __shared__ float tile[32][33];
    const int cb = blockIdx.x * 32;
    const int rb = blockIdx.y * 32;
    for (int i = threadIdx.y; i < 32; i += 8) {
        int r = rb + i, c = cb + threadIdx.x;
        if (r < NITEMS && c < BATCH) {
            size_t base = (size_t)r * BATCH + c;
            float s = 0.f;
            #pragma unroll
            for (int k = 0; k <= ORDER; ++k)
                s += cf.v[k] * __half2float(tauHall[(size_t)k * SLOT + base]);
            tile[i][threadIdx.x] = s;
        }
    }
    __syncthreads();
    for (int i = threadIdx.y; i < 32; i += 8) {
        int c = cb + i, r = rb + threadIdx.x;
        if (c < BATCH && r < NITEMS) {
            int d = ideg[r];
            float v = (d > 0) ? sqrtf((float)d) * tile[threadIdx.x][i]
                              : csum * signal[(size_t)c * NITEMS + r];
            out[(size_t)c * NITEMS + r] = v;
        }
    }
}

// ---------------------------------------------------------------------------
// SpMMs (R14 cores, rows taken from perm[] so co-scheduled rows share n)
// ---------------------------------------------------------------------------

// user side (2 rows/wave): y[u] = (1/deg_u) * sum tauH[col]
__global__ void spmm_user(const int* __restrict__ ptr, const int* __restrict__ deg,
                          const int* __restrict__ perm, const int* __restrict__ idx,
                          const Half4* __restrict__ tauH, Half4* __restrict__ y) {
    const int lane = threadIdx.x & 63;
    const int w = (blockIdx.x * blockDim.x + threadIdx.x) >> 6;
    const int H = NUSERS / 2;
    if (w >= H) return;
    const int r0 = perm[2 * w], r1 = perm[2 * w + 1];
    const int sub = lane >> 4;
    const int bh  = lane & 15;
    const int b0 = ptr[r0], d0 = deg[r0], n0 = (d0 + 15) >> 4;
    const int b1 = ptr[r1], d1 = deg[r1], n1 = (d1 + 15) >> 4;
    int j0 = b0 + (sub << 2), j1 = b1 + (sub << 2);
    float4 a0 = {0.f, 0.f, 0.f, 0.f}, a1 = {0.f, 0.f, 0.f, 0.f};
    const int nmax = max(n0, n1);
    for (int it = 0; it < nmax; ++it) {
        if (it < n0) {
            int i0 = idx[j0], i1 = idx[j0 + 1], i2 = idx[j0 + 2], i3 = idx[j0 + 3];
            Half4 v0 = tauH[(size_t)i0 * 16 + bh];
            Half4 v1 = tauH[(size_t)i1 * 16 + bh];
            Half4 v2 = tauH[(size_t)i2 * 16 + bh];
            Half4 v3 = tauH[(size_t)i3 * 16 + bh];
            acc_pk(a0, v0, v1, v2, v3);
            j0 += 16;
        }
        if (it < n1) {
            int i0 = idx[j1], i1 = idx[j1 + 1], i2 = idx[j1 + 2], i3 = idx[j1 + 3];
            Half4 v0 = tauH[(size_t)i0 * 16 + bh];
            Half4 v1 = tauH[(size_t)i1 * 16 + bh];
            Half4 v2 = tauH[(size_t)i2 * 16 + bh];
            Half4 v3 = tauH[(size_t)i3 * 16 + bh];
            acc_pk(a1, v0, v1, v2, v3);
            j1 += 16;
        }
    }
    a0.x += __shfl_xor(a0.x, 16); a0.y += __shfl_xor(a0.y, 16);
    a0.z += __shfl_xor(a0.z, 16); a0.w += __shfl_xor(a0.w, 16);
    a0.x += __shfl_xor(a0.x, 32); a0.y += __shfl_xor(a0.y, 32);
    a0.z += __shfl_xor(a0.z, 32); a0.w += __shfl_xor(a0.w, 32);
    a1.x += __shfl_xor(a1.x, 16); a1.y += __shfl_xor(a1.y, 16);
    a1.z += __shfl_xor(a1.z, 16); a1.w += __shfl_xor(a1.w, 16);
    a1.x += __shfl_xor(a1.x, 32); a1.y += __shfl_xor(a1.y, 32);
    a1.z += __shfl_xor(a1.z, 32); a1.w += __shfl_xor(a1.w, 32);
    if (sub == 0) {
        float s0 = (d0 > 0) ? 1.0f / (float)d0 : 0.0f;
        y[(size_t)r0 * 16 + bh] = to_h4(s0 * a0.x, s0 * a0.y, s0 * a0.z, s0 * a0.w);
        float s1 = (d1 > 0) ? 1.0f / (float)d1 : 0.0f;
        y[(size_t)r1 * 16 + bh] = to_h4(s1 * a1.x, s1 * a1.y, s1 * a1.z, s1 * a1.w);
    }
}

// item-side gather core: 4 rows/wave, padded, no tails
__device__ __forceinline__ void gather4_p(const int* __restrict__ idx,
                                          const Half4* __restrict__ y,
                                          const int* b, const int* n,
                                          int sub, int bh, float4* a) {
    int j[4];
    int nmax = 0;
    #pragma unroll
    for (int q = 0; q < 4; ++q) {
        j[q] = b[q] + (sub << 2);
        nmax = max(nmax, n[q]);
    }
    for (int it = 0; it < nmax; ++it) {
        #pragma unroll
        for (int q = 0; q < 4; ++q) {
            if (it < n[q]) {
                int i0 = idx[j[q]], i1 = idx[j[q] + 1];
                int i2 = idx[j[q] + 2], i3 = idx[j[q] + 3];
                Half4 v0 = y[(size_t)i0 * 16 + bh];
                Half4 v1 = y[(size_t)i1 * 16 + bh];
                Half4 v2 = y[(size_t)i2 * 16 + bh];
                Half4 v3 = y[(size_t)i3 * 16 + bh];
                acc_pk(a[q], v0, v1, v2, v3);
                j[q] += 16;
            }
        }
    }
    #pragma unroll
    for (int q = 0; q < 4; ++q) {
        a[q].x += __shfl_xor(a[q].x, 16); a[q].y += __shfl_xor(a[q].y, 16);
        a[q].z += __shfl_xor(a[q].z, 16); a[q].w += __shfl_xor(a[q].w, 16);
        a[q].x += __shfl_xor(a[q].x, 32); a[q].y += __shfl_xor(a[q].y, 32);
        a[q].z += __shfl_xor(a[q].z, 32); a[q].w += __shfl_xor(a[q].w, 32);
    }
}

// item, first step: tau1 = tau0 - (2/deg)*z ; write fp32 + fp16
__global__ void spmm_item_first(const int* __restrict__ ptr, const int* __restrict__ deg,
                                const int* __restrict__ perm, const int* __restrict__ idx,
                                const Half4* __restrict__ y,
                                const float* __restrict__ tau0, float* __restrict__ tau1,
                                Half4* __restrict__ tauH1) {
    const int lane = threadIdx.x & 63;
    const int w = (blockIdx.x * blockDim.x + threadIdx.x) >> 6;
    const int H = NITEMS / 4;
    if (w >= H) return;
    int r[4] = {perm[4 * w], perm[4 * w + 1], perm[4 * w + 2], perm[4 * w + 3]};
    const int sub = lane >> 4;
    const int bh  = lane & 15;
    int b[4], d[4], n[4];
    #pragma unroll
    for (int q = 0; q < 4; ++q) {
        b[q] = ptr[r[q]];
        d[q] = deg[r[q]];
        n[q] = (d[q] + 15) >> 4;
    }
    float4 a[4] = {{0,0,0,0},{0,0,0,0},{0,0,0,0},{0,0,0,0}};
    gather4_p(idx, y, b, n, sub, bh, a);
    if (sub == 0) {
        #pragma unroll
        for (int q = 0; q < 4; ++q) {
            float inv = (d[q] > 0) ? 1.0f / (float)d[q] : 0.0f;
            float s2 = 2.0f * inv;
            size_t base = (size_t)r[q] * BATCH + (bh << 2);
            float4 t0v = *(const float4*)&tau0[base];
            float4 t;
            t.x = t0v.x - s2 * a[q].x; t.y = t0v.y - s2 * a[q].y;
            t.z = t0v.z - s2 * a[q].z; t.w = t0v.w - s2 * a[q].w;
            *(float4*)&tau1[base] = t;
            tauH1[(size_t)r[q] * 16 + bh] = to_h4(t.x, t.y, t.z, t.w);
        }
    }
}

// item, general step: t2 = 2*t1 - (4/deg)*z - t0 ; write fp32 + fp16
__global__ void spmm_item_k(const int* __restrict__ ptr, const int* __restrict__ deg,
                            const int* __restrict__ perm, const int* __restrict__ idx,
                            const Half4* __restrict__ y,
                            const float* __restrict__ tau1, float* __restrict__ tau0,
                            Half4* __restrict__ tauHk) {
    const int lane = threadIdx.x & 63;
    const int w = (blockIdx.x * blockDim.x + threadIdx.x) >> 6;
    const int H = NITEMS / 4;
    if (w >= H) return;
    int r[4] = {perm[4 * w], perm[4 * w + 1], perm[4 * w + 2], perm[4 * w + 3]};
    const int sub = lane >> 4;
    const int bh  = lane & 15;
    int b[4], d[4], n[4];
    #pragma unroll
    for (int q = 0; q < 4; ++q) {
        b[q] = ptr[r[q]];
        d[q] = deg[r[q]];
        n[q] = (d[q] + 15) >> 4;
    }
    float4 a[4] = {{0,0,0,0},{0,0,0,0},{0,0,0,0},{0,0,0,0}};
    gather4_p(idx, y, b, n, sub, bh, a);
    if (sub == 0) {
        #pragma unroll
        for (int q = 0; q < 4; ++q) {
            float inv = (d[q] > 0) ? 1.0f / (float)d[q] : 0.0f;
            float s4 = 4.0f * inv;
            size_t base = (size_t)r[q] * BATCH + (bh << 2);
            float4 t1v = *(const float4*)&tau1[base];
            float4 t0v = *(const float4*)&tau0[base];
            float4 t2;
            t2.x = 2.0f * t1v.x - s4 * a[q].x - t0v.x;
            t2.y = 2.0f * t1v.y - s4 * a[q].y - t0v.y;
            t2.z = 2.0f * t1v.z - s4 * a[q].z - t0v.z;
            t2.w = 2.0f * t1v.w - s4 * a[q].w - t0v.w;
            *(float4*)&tau0[base] = t2;
            tauHk[(size_t)r[q] * 16 + bh] = to_h4(t2.x, t2.y, t2.z, t2.w);
        }
    }
}

// ---------------------------------------------------------------------------
// Host-side exact replica of reference cheby_coeffs
// ---------------------------------------------------------------------------
static void cheby_coeffs_host(float* c) {
    const int order = ORDER, flatness = 2;
    const double PI = 3.14159265358979323846;
    double tgt[ORDER + 1], nodes[ORDER + 1];
    for (int x = 0; x <= order; ++x) {
        double xv = cos((double)(order - x) / order * PI);
        xv = nearbyint(xv * 1000.0) / 1000.0;
        double t = (xv < 0.0) ? pow(-xv, (double)flatness) * 0.5 + 0.5
                              : pow(xv, (double)flatness) * (-0.5) + 0.5;
        tgt[x] = nearbyint(t * 1000.0) / 1000.0;
    }
    for (int k = 1; k <= order + 1; ++k)
        nodes[k - 1] = cos((order + 1 + 0.5 - k) / (double)(order + 1) * PI);

    double prev[ORDER + 1], cur[ORDER + 1], nxt[ORDER + 1];
    double sums[ORDER + 1];
    double s0 = 0, s1 = 0;
    for (int i = 0; i <= order; ++i) {
        prev[i] = tgt[i];
        cur[i]  = nodes[i] * tgt[i];
        s0 += prev[i];
        s1 += cur[i];
    }
    sums[0] = s0; sums[1] = s1;
    for (int j = 2; j <= order; ++j) {
        double s = 0;
        for (int i = 0; i <= order; ++i) {
            nxt[i] = nodes[i] * cur[i] * 2.0 - prev[i];
            s += nxt[i];
        }
        sums[j] = s;
        for (int i = 0; i <= order; ++i) { prev[i] = cur[i]; cur[i] = nxt[i]; }
    }
    for (int j = 0; j <= order; ++j)
        c[j] = (float)(sums[j] * (2.0 / (order + 1)));
    c[0] *= 0.5f;
}

extern "C" void kernel_launch(void* const* d_in, const int* in_sizes, int n_in,
                              void* d_out, int out_size, void* d_ws, size_t ws_size,
                              hipStream_t stream) {
    const float* signal = (const float*)d_in[0];   // [BATCH, NITEMS]
    const int*   row    = (const int*)d_in[2];     // [NNZ] -> users
    const int*   col    = (const int*)d_in[3];     // [NNZ] -> items
    const int nnz = in_sizes[1];

    char* wsb = (char*)d_ws;
    size_t off = 0;
    auto carve = [&](size_t nbytes) {
        void* p = wsb + off;
        off += (nbytes + 255) & ~(size_t)255;
        return p;
    };
    const size_t NB = (size_t)NITEMS * BATCH;
    const size_t NEU = (size_t)NBUCKU * CAPU;
    const size_t NEI = (size_t)NBUCKI * CAPI;
    float*  tauA   = (float*)carve(NB * 4);
    float*  tauB   = (float*)carve(NB * 4);
    __half* tauHall = (__half*)carve((ORDER + 1) * SLOT * 2);
    Half4*  ybuf   = (Half4*)carve(((size_t)NUSERS + 1) * BATCH * 2);
    int*    uptr   = (int*)carve(NUSERS * 4);
    int*    iptr   = (int*)carve(NITEMS * 4);
    int*    udeg   = (int*)carve(NUSERS * 4);
    int*    ideg   = (int*)carve(NITEMS * 4);
    int*    bcurU  = (int*)carve(NBUCKU * 4);
    int*    bcurI  = (int*)carve(NBUCKI * 4);
    int*    bins   = (int*)carve(4 * NBIN * 4);    // gcntU,gcurU,gcntI,gcurI
    int*    uperm  = (int*)carve(NUSERS * 4);
    int*    iperm  = (int*)carve(NITEMS * 4);
    int*    ucol   = (int*)carve(NEU * 4);
    int*    irow   = (int*)carve(NEI * 4);
    int*    stU    = (int*)tauHall;                // staging aliases tauHall
    int*    stI    = (int*)tauHall + NEU;
    (void)ws_size;

    float c[ORDER + 1];
    cheby_coeffs_host(c);
    Coeffs cf;
    float csum = 0.f;
    for (int k = 0; k <= ORDER; ++k) { cf.v[k] = c[k]; csum += c[k]; }

    // ---- CSR build ----
    init_bcur<<<(NBUCKU + 255) / 256, 256, 0, stream>>>(bcurU, bcurI, bins);
    scatter1<<<S1_BLOCKS, 256, 0, stream>>>(row, col, bcurU, bcurI, stU, stI, nnz);
    scatter2<<<NBUCKU, 256, 0, stream>>>(bcurU, stU, uptr, udeg, ucol, NUSERS, CAPU, NITEMS);
    scatter2<<<NBUCKI, 256, 0, stream>>>(bcurI, stI, iptr, ideg, irow, NITEMS, CAPI, NUSERS);
    zero_pads<<<1, 256, 0, stream>>>(tauHall, (__half*)ybuf);

    // ---- bin-sort rows by padded iter count ----
    bin_count<<<BIN_BLOCKS, 256, 0, stream>>>(udeg, NUSERS, bins);
    bin_count<<<BIN_BLOCKS, 256, 0, stream>>>(ideg, NITEMS, bins + 2 * NBIN);
    bin_scan<<<1, 64, 0, stream>>>(bins);
    bin_scatter<<<BIN_BLOCKS, 256, 0, stream>>>(udeg, NUSERS, bins + NBIN, uperm);
    bin_scatter<<<BIN_BLOCKS, 256, 0, stream>>>(ideg, NITEMS, bins + 3 * NBIN, iperm);

    // ---- tau0 (fp32 + fp16 slot 0) ----
    dim3 tb(32, 8);
    transpose_scale_k<<<dim3((NITEMS + 31) / 32, (BATCH + 31) / 32), tb, 0, stream>>>(
        signal, ideg, tauA, tauHall);

    const int ug = ((NUSERS / 2) * 64 + 255) / 256;   // user: 2 rows/wave
    const int ig = ((NITEMS / 4) * 64 + 255) / 256;   // item: 4 rows/wave

    // ---- k = 1 ----
    spmm_user<<<ug, 256, 0, stream>>>(uptr, udeg, uperm, ucol, (const Half4*)tauHall, ybuf);
    spmm_item_first<<<ig, 256, 0, stream>>>(iptr, ideg, iperm, irow, ybuf, tauA, tauB,
                                            (Half4*)(tauHall + SLOT));

    float* t0 = tauA;
    float* t1 = tauB;
    for (int k = 2; k <= ORDER; ++k) {
        spmm_user<<<ug, 256, 0, stream>>>(uptr, udeg, uperm, ucol,
                                          (const Half4*)(tauHall + (size_t)(k - 1) * SLOT), ybuf);
        spmm_item_k<<<ig, 256, 0, stream>>>(iptr, ideg, iperm, irow, ybuf, t1, t0,
                                            (Half4*)(tauHall + (size_t)k * SLOT));
        float* tmp = t0; t0 = t1; t1 = tmp;
    }

    // ---- d_out = sqrt(di) * sum_k c_k tauH_k, transposed ----
    transpose_out_k<<<dim3((BATCH + 31) / 32, (NITEMS + 31) / 32), tb, 0, stream>>>(
        tauHall, signal, ideg, csum, cf, (float*)d_out);
}

// Round 17
// 768.065 us; speedup vs baseline: 1.1835x; 1.0490x over previous
//
#include <hip/hip_runtime.h>
#include <hip/hip_fp16.h>
#include <math.h>

#define NUSERS 100000
#define NITEMS 50000
#define BATCH  64
#define ORDER  8
#define BSHIFT 9                                   // 512 rows per bucket
#define BROWS  (1 << BSHIFT)
#define NBUCKU ((NUSERS + BROWS - 1) >> BSHIFT)    // 196
#define NBUCKI ((NITEMS + BROWS - 1) >> BSHIFT)    // 98
#define CAPU 16384
#define CAPI 24576
#define S1_BLOCKS 512
#define NREP 4

// ---------------------------------------------------------------------------
// R14 structure (best: 771us). R15 (16B/lane) and R16 (bin-sort) both
// regressed -- lines/instr is width-invariant; wave imbalance is absorbed by
// TLP. R17: the one untested cell -- user SpMM at 4 rows/wave. R12's 4-row
// user failed on serial deg%16 tails; R14's padding removed tails, so 4-row
// user now doubles in-flight gathers (16) at item's proven VGPR cost.
// ---------------------------------------------------------------------------

struct __align__(8) Half4 { __half2 a, b; };
struct Coeffs { float v[ORDER + 1]; };

#define SLOT ((size_t)(NITEMS + 1) * BATCH)        // fp16 tau slot incl. zero row

__device__ __forceinline__ void acc_pk(float4& acc, Half4 v0, Half4 v1,
                                       Half4 v2, Half4 v3) {
    __half2 sa = __hadd2(__hadd2(v0.a, v1.a), __hadd2(v2.a, v3.a));
    __half2 sb = __hadd2(__hadd2(v0.b, v1.b), __hadd2(v2.b, v3.b));
    float2 fa = __half22float2(sa);
    float2 fb = __half22float2(sb);
    acc.x += fa.x; acc.y += fa.y; acc.z += fb.x; acc.w += fb.y;
}

__device__ __forceinline__ Half4 to_h4(float x, float y, float z, float w) {
    Half4 h;
    h.a = __floats2half2_rn(x, y);
    h.b = __floats2half2_rn(z, w);
    return h;
}

// ---------------------------------------------------------------------------
// CSR build (R14)
// ---------------------------------------------------------------------------
__global__ void init_bcur(int* __restrict__ bcurU, int* __restrict__ bcurI) {
    int t = blockIdx.x * blockDim.x + threadIdx.x;
    if (t < NBUCKU) bcurU[t] = t * CAPU;
    if (t < NBUCKI) bcurI[t] = t * CAPI;
}

__global__ void zero_pads(__half* __restrict__ tauHall, __half* __restrict__ ybuf) {
    int t = threadIdx.x;
    for (int k = 0; k <= ORDER; ++k)
        if (t < BATCH) tauHall[(size_t)k * SLOT + (size_t)NITEMS * BATCH + t] = __float2half(0.f);
    if (t < BATCH) ybuf[(size_t)NUSERS * BATCH + t] = __float2half(0.f);
}

__global__ void scatter1(const int* __restrict__ row, const int* __restrict__ col,
                         int* __restrict__ bcurU, int* __restrict__ bcurI,
                         int* __restrict__ stU, int* __restrict__ stI, int nnz) {
    __shared__ int cU[NREP][NBUCKU];
    __shared__ int cI[NREP][NBUCKI];
    const int chunk = (nnz + S1_BLOCKS - 1) / S1_BLOCKS;
    const int b0 = blockIdx.x * chunk;
    const int e0 = min(b0 + chunk, nnz);
    const int sw = threadIdx.x >> 6;
    for (int t = threadIdx.x; t < NREP * NBUCKU; t += blockDim.x) (&cU[0][0])[t] = 0;
    for (int t = threadIdx.x; t < NREP * NBUCKI; t += blockDim.x) (&cI[0][0])[t] = 0;
    __syncthreads();
    for (int i = b0 + threadIdx.x; i < e0; i += blockDim.x) {
        atomicAdd(&cU[sw][row[i] >> BSHIFT], 1);
        atomicAdd(&cI[sw][col[i] >> BSHIFT], 1);
    }
    __syncthreads();
    for (int t = threadIdx.x; t < NBUCKU; t += blockDim.x) {
        int c0 = cU[0][t], c1 = cU[1][t], c2 = cU[2][t], c3 = cU[3][t];
        int tot = c0 + c1 + c2 + c3;
        int base = (tot > 0) ? atomicAdd(&bcurU[t], tot) : 0;
        cU[0][t] = base;
        cU[1][t] = base + c0;
        cU[2][t] = base + c0 + c1;
        cU[3][t] = base + c0 + c1 + c2;
    }
    for (int t = threadIdx.x; t < NBUCKI; t += blockDim.x) {
        int c0 = cI[0][t], c1 = cI[1][t], c2 = cI[2][t], c3 = cI[3][t];
        int tot = c0 + c1 + c2 + c3;
        int base = (tot > 0) ? atomicAdd(&bcurI[t], tot) : 0;
        cI[0][t] = base;
        cI[1][t] = base + c0;
        cI[2][t] = base + c0 + c1;
        cI[3][t] = base + c0 + c1 + c2;
    }
    __syncthreads();
    for (int i = b0 + threadIdx.x; i < e0; i += blockDim.x) {
        int r = row[i], c = col[i];
        int pu = atomicAdd(&cU[sw][r >> BSHIFT], 1);
        stU[pu] = ((r & (BROWS - 1)) << 17) | c;
        int pi = atomicAdd(&cI[sw][c >> BSHIFT], 1);
        stI[pi] = ((c & (BROWS - 1)) << 17) | r;
    }
}

__global__ void scatter2(const int* __restrict__ bcur, const int* __restrict__ st,
                         int* __restrict__ ptr, int* __restrict__ degOut,
                         int* __restrict__ outIdx, int nrows, int cap, int dummyIdx) {
    __shared__ int deg[BROWS];
    __shared__ int ps[256];
    __shared__ int cur[BROWS];
    __shared__ int rs[BROWS];
    const int rbase = blockIdx.x << BSHIFT;
    const int nr = min(BROWS, nrows - rbase);
    const int lo = blockIdx.x * cap;
    const int hi = bcur[blockIdx.x];
    const int t = threadIdx.x;
    deg[2 * t] = 0;
    deg[2 * t + 1] = 0;
    __syncthreads();
    for (int j = lo + t; j < hi; j += 256)
        atomicAdd(&deg[st[j] >> 17], 1);
    __syncthreads();
    int a = deg[2 * t];
    int b = deg[2 * t + 1];
    int pa = (a + 15) & ~15;
    int pb = (b + 15) & ~15;
    ps[t] = pa + pb;
    __syncthreads();
    for (int off = 1; off < 256; off <<= 1) {
        int u = (t >= off) ? ps[t - off] : 0;
        __syncthreads();
        ps[t] += u;
        __syncthreads();
    }
    int excl = (t > 0) ? ps[t - 1] : 0;
    int p0 = lo + excl;
    int p1 = p0 + pa;
    rs[2 * t] = p0;
    rs[2 * t + 1] = p1;
    cur[2 * t] = p0;
    cur[2 * t + 1] = p1;
    if (2 * t < nr)     { ptr[rbase + 2 * t] = p0;     degOut[rbase + 2 * t] = a; }
    if (2 * t + 1 < nr) { ptr[rbase + 2 * t + 1] = p1; degOut[rbase + 2 * t + 1] = b; }
    __syncthreads();
    for (int j = lo + t; j < hi; j += 256) {
        int v = st[j];
        int p = atomicAdd(&cur[v >> 17], 1);
        outIdx[p] = v & 0x1FFFF;
    }
    __syncthreads();
    for (int i = t; i < nr; i += 256) {
        int endReal = cur[i];
        int endPad  = rs[i] + ((deg[i] + 15) & ~15);
        for (int j = endReal; j < endPad; ++j) outIdx[j] = dummyIdx;
    }
}

// ---------------------------------------------------------------------------
// transposes (R14)
// ---------------------------------------------------------------------------
__global__ void transpose_scale_k(const float* __restrict__ in,
                                  const int* __restrict__ ideg,
                                  float* __restrict__ out,
                                  __half* __restrict__ outH) {
    __shared__ float tile[32][33];
    const int cb = blockIdx.x * 32;
    const int rb = blockIdx.y * 32;
    for (int i = threadIdx.y; i < 32; i += 8) {
        int r = rb + i, c = cb + threadIdx.x;
        if (r < BATCH && c < NITEMS) tile[i][threadIdx.x] = in[(size_t)r * NITEMS + c];
    }
    __syncthreads();
    for (int i = threadIdx.y; i < 32; i += 8) {
        int c = cb + i, r = rb + threadIdx.x;
        if (c < NITEMS && r < BATCH) {
            int d = ideg[c];
            float dis = (d > 0) ? rsqrtf((float)d) : 0.0f;
            float v = dis * tile[threadIdx.x][i];
            out[(size_t)c * BATCH + r] = v;
            outH[(size_t)c * BATCH + r] = __float2half(v);
        }
    }
}

__global__ void transpose_out_k(const __half* __restrict__ tauHall,
                                const float* __restrict__ signal,
                                const int* __restrict__ ideg, float csum, Coeffs cf,
                                float* __restrict__ out) {
    __shared__ float tile[32][33];
    const int cb = blockIdx.x * 32;
    const int rb = blockIdx.y * 32;
    for (int i = threadIdx.y; i < 32; i += 8) {
        int r = rb + i, c = cb + threadIdx.x;
        if (r < NITEMS && c < BATCH) {
            size_t base = (size_t)r * BATCH + c;
            float s = 0.f;
            #pragma unroll
            for (int k = 0; k <= ORDER; ++k)
                s += cf.v[k] * __half2float(tauHall[(size_t)k * SLOT + base]);
            tile[i][threadIdx.x] = s;
        }
    }
    __syncthreads();
    for (int i = threadIdx.y; i < 32; i += 8) {
        int c = cb + i, r = rb + threadIdx.x;
        if (c < BATCH && r < NITEMS) {
            int d = ideg[r];
            float v = (d > 0) ? sqrtf((float)d) * tile[threadIdx.x][i]
                              : csum * signal[(size_t)c * NITEMS + r];
            out[(size_t)c * NITEMS + r] = v;
        }
    }
}

// ---------------------------------------------------------------------------
// 4-row gather core (shared): padded rows, exactly n=(deg+15)>>4 iters.
// ---------------------------------------------------------------------------
__device__ __forceinline__ void gather4_p(const int* __restrict__ idx,
                                          const Half4* __restrict__ x,
                                          const int* b, const int* n,
                                          int sub, int bh, float4* a) {
    int j[4];
    int nmax = 0;
    #pragma unroll
    for (int q = 0; q < 4; ++q) {
        j[q] = b[q] + (sub << 2);
        nmax = max(nmax, n[q]);
    }
    for (int it = 0; it < nmax; ++it) {
        #pragma unroll
        for (int q = 0; q < 4; ++q) {
            if (it < n[q]) {
                int i0 = idx[j[q]], i1 = idx[j[q] + 1];
                int i2 = idx[j[q] + 2], i3 = idx[j[q] + 3];
                Half4 v0 = x[(size_t)i0 * 16 + bh];
                Half4 v1 = x[(size_t)i1 * 16 + bh];
                Half4 v2 = x[(size_t)i2 * 16 + bh];
                Half4 v3 = x[(size_t)i3 * 16 + bh];
                acc_pk(a[q], v0, v1, v2, v3);
                j[q] += 16;
            }
        }
    }
    #pragma unroll
    for (int q = 0; q < 4; ++q) {
        a[q].x += __shfl_xor(a[q].x, 16); a[q].y += __shfl_xor(a[q].y, 16);
        a[q].z += __shfl_xor(a[q].z, 16); a[q].w += __shfl_xor(a[q].w, 16);
        a[q].x += __shfl_xor(a[q].x, 32); a[q].y += __shfl_xor(a[q].y, 32);
        a[q].z += __shfl_xor(a[q].z, 32); a[q].w += __shfl_xor(a[q].w, 32);
    }
}

// user side (4 rows/wave, padded): y[u] = (1/deg_u) * sum tauH[col]
__global__ void spmm_user(const int* __restrict__ ptr, const int* __restrict__ deg,
                          const int* __restrict__ idx,
                          const Half4* __restrict__ tauH, Half4* __restrict__ y) {
    const int lane = threadIdx.x & 63;
    const int w = (blockIdx.x * blockDim.x + threadIdx.x) >> 6;
    const int H = NUSERS / 4;
    if (w >= H) return;
    int r[4] = {w, w + H, w + 2 * H, w + 3 * H};
    const int sub = lane >> 4;
    const int bh  = lane & 15;
    int b[4], d[4], n[4];
    #pragma unroll
    for (int q = 0; q < 4; ++q) {
        b[q] = ptr[r[q]];
        d[q] = deg[r[q]];
        n[q] = (d[q] + 15) >> 4;
    }
    float4 a[4] = {{0,0,0,0},{0,0,0,0},{0,0,0,0},{0,0,0,0}};
    gather4_p(idx, tauH, b, n, sub, bh, a);
    if (sub == 0) {
        #pragma unroll
        for (int q = 0; q < 4; ++q) {
            float s = (d[q] > 0) ? 1.0f / (float)d[q] : 0.0f;
            y[(size_t)r[q] * 16 + bh] = to_h4(s * a[q].x, s * a[q].y, s * a[q].z, s * a[q].w);
        }
    }
}

// item, first step: tau1 = tau0 - (2/deg)*z ; write fp32 + fp16
__global__ void spmm_item_first(const int* __restrict__ ptr, const int* __restrict__ deg,
                                const int* __restrict__ idx, const Half4* __restrict__ y,
                                const float* __restrict__ tau0, float* __restrict__ tau1,
                                Half4* __restrict__ tauH1) {
    const int lane = threadIdx.x & 63;
    const int w = (blockIdx.x * blockDim.x + threadIdx.x) >> 6;
    const int H = NITEMS / 4;
    if (w >= H) return;
    int r[4] = {w, w + H, w + 2 * H, w + 3 * H};
    const int sub = lane >> 4;
    const int bh  = lane & 15;
    int b[4], d[4], n[4];
    #pragma unroll
    for (int q = 0; q < 4; ++q) {
        b[q] = ptr[r[q]];
        d[q] = deg[r[q]];
        n[q] = (d[q] + 15) >> 4;
    }
    float4 a[4] = {{0,0,0,0},{0,0,0,0},{0,0,0,0},{0,0,0,0}};
    gather4_p(idx, y, b, n, sub, bh, a);
    if (sub == 0) {
        #pragma unroll
        for (int q = 0; q < 4; ++q) {
            float inv = (d[q] > 0) ? 1.0f / (float)d[q] : 0.0f;
            float s2 = 2.0f * inv;
            size_t base = (size_t)r[q] * BATCH + (bh << 2);
            float4 t0v = *(const float4*)&tau0[base];
            float4 t;
            t.x = t0v.x - s2 * a[q].x; t.y = t0v.y - s2 * a[q].y;
            t.z = t0v.z - s2 * a[q].z; t.w = t0v.w - s2 * a[q].w;
            *(float4*)&tau1[base] = t;
            tauH1[(size_t)r[q] * 16 + bh] = to_h4(t.x, t.y, t.z, t.w);
        }
    }
}

// item, general step: t2 = 2*t1 - (4/deg)*z - t0 ; write fp32 + fp16
__global__ void spmm_item_k(const int* __restrict__ ptr, const int* __restrict__ deg,
                            const int* __restrict__ idx, const Half4* __restrict__ y,
                            const float* __restrict__ tau1, float* __restrict__ tau0,
                            Half4* __restrict__ tauHk) {
    const int lane = threadIdx.x & 63;
    const int w = (blockIdx.x * blockDim.x + threadIdx.x) >> 6;
    const int H = NITEMS / 4;
    if (w >= H) return;
    int r[4] = {w, w + H, w + 2 * H, w + 3 * H};
    const int sub = lane >> 4;
    const int bh  = lane & 15;
    int b[4], d[4], n[4];
    #pragma unroll
    for (int q = 0; q < 4; ++q) {
        b[q] = ptr[r[q]];
        d[q] = deg[r[q]];
        n[q] = (d[q] + 15) >> 4;
    }
    float4 a[4] = {{0,0,0,0},{0,0,0,0},{0,0,0,0},{0,0,0,0}};
    gather4_p(idx, y, b, n, sub, bh, a);
    if (sub == 0) {
        #pragma unroll
        for (int q = 0; q < 4; ++q) {
            float inv = (d[q] > 0) ? 1.0f / (float)d[q] : 0.0f;
            float s4 = 4.0f * inv;
            size_t base = (size_t)r[q] * BATCH + (bh << 2);
            float4 t1v = *(const float4*)&tau1[base];
            float4 t0v = *(const float4*)&tau0[base];
            float4 t2;
            t2.x = 2.0f * t1v.x - s4 * a[q].x - t0v.x;
            t2.y = 2.0f * t1v.y - s4 * a[q].y - t0v.y;
            t2.z = 2.0f * t1v.z - s4 * a[q].z - t0v.z;
            t2.w = 2.0f * t1v.w - s4 * a[q].w - t0v.w;
            *(float4*)&tau0[base] = t2;
            tauHk[(size_t)r[q] * 16 + bh] = to_h4(t2.x, t2.y, t2.z, t2.w);
        }
    }
}

// ---------------------------------------------------------------------------
// Host-side exact replica of reference cheby_coeffs
// ---------------------------------------------------------------------------
static void cheby_coeffs_host(float* c) {
    const int order = ORDER, flatness = 2;
    const double PI = 3.14159265358979323846;
    double tgt[ORDER + 1], nodes[ORDER + 1];
    for (int x = 0; x <= order; ++x) {
        double xv = cos((double)(order - x) / order * PI);
        xv = nearbyint(xv * 1000.0) / 1000.0;
        double t = (xv < 0.0) ? pow(-xv, (double)flatness) * 0.5 + 0.5
                              : pow(xv, (double)flatness) * (-0.5) + 0.5;
        tgt[x] = nearbyint(t * 1000.0) / 1000.0;
    }
    for (int k = 1; k <= order + 1; ++k)
        nodes[k - 1] = cos((order + 1 + 0.5 - k) / (double)(order + 1) * PI);

    double prev[ORDER + 1], cur[ORDER + 1], nxt[ORDER + 1];
    double sums[ORDER + 1];
    double s0 = 0, s1 = 0;
    for (int i = 0; i <= order; ++i) {
        prev[i] = tgt[i];
        cur[i]  = nodes[i] * tgt[i];
        s0 += prev[i];
        s1 += cur[i];
    }
    sums[0] = s0; sums[1] = s1;
    for (int j = 2; j <= order; ++j) {
        double s = 0;
        for (int i = 0; i <= order; ++i) {
            nxt[i] = nodes[i] * cur[i] * 2.0 - prev[i];
            s += nxt[i];
        }
        sums[j] = s;
        for (int i = 0; i <= order; ++i) { prev[i] = cur[i]; cur[i] = nxt[i]; }
    }
    for (int j = 0; j <= order; ++j)
        c[j] = (float)(sums[j] * (2.0 / (order + 1)));
    c[0] *= 0.5f;
}

extern "C" void kernel_launch(void* const* d_in, const int* in_sizes, int n_in,
                              void* d_out, int out_size, void* d_ws, size_t ws_size,
                              hipStream_t stream) {
    const float* signal = (const float*)d_in[0];   // [BATCH, NITEMS]
    const int*   row    = (const int*)d_in[2];     // [NNZ] -> users
    const int*   col    = (const int*)d_in[3];     // [NNZ] -> items
    const int nnz = in_sizes[1];

    char* wsb = (char*)d_ws;
    size_t off = 0;
    auto carve = [&](size_t nbytes) {
        void* p = wsb + off;
        off += (nbytes + 255) & ~(size_t)255;
        return p;
    };
    const size_t NB = (size_t)NITEMS * BATCH;
    const size_t NEU = (size_t)NBUCKU * CAPU;
    const size_t NEI = (size_t)NBUCKI * CAPI;
    float*  tauA   = (float*)carve(NB * 4);
    float*  tauB   = (float*)carve(NB * 4);
    __half* tauHall = (__half*)carve((ORDER + 1) * SLOT * 2);
    Half4*  ybuf   = (Half4*)carve(((size_t)NUSERS + 1) * BATCH * 2);
    int*    uptr   = (int*)carve(NUSERS * 4);
    int*    iptr   = (int*)carve(NITEMS * 4);
    int*    udeg   = (int*)carve(NUSERS * 4);
    int*    ideg   = (int*)carve(NITEMS * 4);
    int*    bcurU  = (int*)carve(NBUCKU * 4);
    int*    bcurI  = (int*)carve(NBUCKI * 4);
    int*    ucol   = (int*)carve(NEU * 4);
    int*    irow   = (int*)carve(NEI * 4);
    int*    stU    = (int*)tauHall;                // staging aliases tauHall
    int*    stI    = (int*)tauHall + NEU;
    (void)ws_size;

    float c[ORDER + 1];
    cheby_coeffs_host(c);
    Coeffs cf;
    float csum = 0.f;
    for (int k = 0; k <= ORDER; ++k) { cf.v[k] = c[k]; csum += c[k]; }

    // ---- CSR build ----
    init_bcur<<<(NBUCKU + 255) / 256, 256, 0, stream>>>(bcurU, bcurI);
    scatter1<<<S1_BLOCKS, 256, 0, stream>>>(row, col, bcurU, bcurI, stU, stI, nnz);
    scatter2<<<NBUCKU, 256, 0, stream>>>(bcurU, stU, uptr, udeg, ucol, NUSERS, CAPU, NITEMS);
    scatter2<<<NBUCKI, 256, 0, stream>>>(bcurI, stI, iptr, ideg, irow, NITEMS, CAPI, NUSERS);
    zero_pads<<<1, 256, 0, stream>>>(tauHall, (__half*)ybuf);

    // ---- tau0 (fp32 + fp16 slot 0) ----
    dim3 tb(32, 8);
    transpose_scale_k<<<dim3((NITEMS + 31) / 32, (BATCH + 31) / 32), tb, 0, stream>>>(
        signal, ideg, tauA, tauHall);

    const int ug = ((NUSERS / 4) * 64 + 255) / 256;   // user: 4 rows/wave (padded)
    const int ig = ((NITEMS / 4) * 64 + 255) / 256;   // item: 4 rows/wave

    // ---- k = 1 ----
    spmm_user<<<ug, 256, 0, stream>>>(uptr, udeg, ucol, (const Half4*)tauHall, ybuf);
    spmm_item_first<<<ig, 256, 0, stream>>>(iptr, ideg, irow, ybuf, tauA, tauB,
                                            (Half4*)(tauHall + SLOT));

    float* t0 = tauA;
    float* t1 = tauB;
    for (int k = 2; k <= ORDER; ++k) {
        spmm_user<<<ug, 256, 0, stream>>>(uptr, udeg, ucol,
                                          (const Half4*)(tauHall + (size_t)(k - 1) * SLOT), ybuf);
        spmm_item_k<<<ig, 256, 0, stream>>>(iptr, ideg, irow, ybuf, t1, t0,
                                            (Half4*)(tauHall + (size_t)k * SLOT));
        float* tmp = t0; t0 = t1; t1 = tmp;
    }

    // ---- d_out = sqrt(di) * sum_k c_k tauH_k, transposed ----
    transpose_out_k<<<dim3((BATCH + 31) / 32, (NITEMS + 31) / 32), tb, 0, stream>>>(
        tauHall, signal, ideg, csum, cf, (float*)d_out);
}